// Round 3
// baseline (206.486 us; speedup 1.0000x reference)
//
#include <hip/hip_runtime.h>

// Fused: z = x @ W^T + b_lin; y = swish(z) + b_ex; GroupNorm(32 groups) * gn_w + gn_b
// x: [8192, 2048] f32, W: [4096, 2048] f32, out: [8192, 4096] f32
// Round 3: m201-style 4-phase/K-tile schedule, counted vmcnt gates coupled to
// barriers, K-split LDS layout (no swizzle needed, bank-balanced), T1+T5.

typedef __attribute__((ext_vector_type(8))) short short8;
typedef __attribute__((ext_vector_type(4))) float f32x4;

#define M_DIM 8192
#define N_DIM 4096
#define K_DIM 2048
#define BM 256
#define BN 256
#define BK 64
#define NT (K_DIM / BK)  // 32

// ---------------- f32 -> bf16 (RNE) convert, 8 elems/thread ----------------
__global__ void f32_to_bf16_k(const float* __restrict__ in, ushort* __restrict__ out, int n8) {
    int i = blockIdx.x * blockDim.x + threadIdx.x;
    if (i >= n8) return;
    const float4* p = (const float4*)in + 2 * (size_t)i;
    float4 a = p[0], b = p[1];
    float v[8] = {a.x, a.y, a.z, a.w, b.x, b.y, b.z, b.w};
    ushort rr[8];
#pragma unroll
    for (int j = 0; j < 8; ++j) {
        unsigned u = __float_as_uint(v[j]);
        rr[j] = (ushort)((u + 0x7fffu + ((u >> 16) & 1u)) >> 16);  // RNE
    }
    uint4 o;
    o.x = (unsigned)rr[0] | ((unsigned)rr[1] << 16);
    o.y = (unsigned)rr[2] | ((unsigned)rr[3] << 16);
    o.z = (unsigned)rr[4] | ((unsigned)rr[5] << 16);
    o.w = (unsigned)rr[6] | ((unsigned)rr[7] << 16);
    ((uint4*)out)[i] = o;
}

// LDS layout per K-tile buffer (32768 ushorts = 64 KiB), ushort offsets:
//   A_k0 [0,8192)  A_k1 [8192,16384)  B_k0 [16384,24576)  B_k1 [24576,32768)
// within a half-block: row-major [256 rows][32 ushorts] (64 B rows).
// Frag read (lane r,h): byte = row*64 + h*16 -> bank bits {h0,h1,row0}: balanced, conflict-free.

#define BAR() __builtin_amdgcn_s_barrier()
#define LGKM0() do { asm volatile("s_waitcnt lgkmcnt(0)" ::: "memory"); __builtin_amdgcn_sched_barrier(0); } while (0)
#define VMC(n_) do { asm volatile("s_waitcnt vmcnt(" #n_ ")" ::: "memory"); __builtin_amdgcn_sched_barrier(0); } while (0)

__global__ __launch_bounds__(512, 2) void gemm_swish_gn(
    const ushort* __restrict__ xb, const ushort* __restrict__ wb,
    const float* __restrict__ bias_lin, const float* __restrict__ bias_extra,
    const float* __restrict__ gn_w, const float* __restrict__ gn_b,
    float* __restrict__ out)
{
    extern __shared__ __align__(16) ushort lds[];  // 2 x 32768 ushorts

    const int t = threadIdx.x;
    const int w = t >> 6;
    const int l = t & 63;
    const int wm = w >> 2;   // 0..1
    const int wn = w & 3;    // 0..3
    const int h = l >> 4;    // 0..3
    const int r = l & 15;    // 0..15

    // T1: XCD-aware bijective swizzle (512 blocks % 8 == 0)
    const int bid = blockIdx.x;
    const int id = (bid & 7) * 64 + (bid >> 3);
    const int brow = id & 31;   // M tile
    const int bcol = id >> 5;   // N tile (= 2 GroupNorm groups)

    // ---- staging source pointers (linear; each STAGE advances K by 32 elems)
    const ushort* pA0 = xb + (size_t)(brow * BM + (t >> 2)) * K_DIM + (t & 3) * 8;
    const ushort* pA1 = pA0 + (size_t)128 * K_DIM;
    const ushort* pB0 = wb + (size_t)(bcol * BN + (t >> 2)) * K_DIM + (t & 3) * 8;
    const ushort* pB1 = pB0 + (size_t)128 * K_DIM;
    const int dst0 = t * 8;  // ushort offset within a 4096-ushort round

#define STAGE_A(slotU) do {                                                   \
    __builtin_amdgcn_global_load_lds(                                         \
        (const __attribute__((address_space(1))) void*)pA0,                   \
        (__attribute__((address_space(3))) void*)&lds[(slotU) + dst0], 16, 0, 0); \
    __builtin_amdgcn_global_load_lds(                                         \
        (const __attribute__((address_space(1))) void*)pA1,                   \
        (__attribute__((address_space(3))) void*)&lds[(slotU) + 4096 + dst0], 16, 0, 0); \
    pA0 += 32; pA1 += 32; } while (0)

#define STAGE_B(slotU) do {                                                   \
    __builtin_amdgcn_global_load_lds(                                         \
        (const __attribute__((address_space(1))) void*)pB0,                   \
        (__attribute__((address_space(3))) void*)&lds[(slotU) + dst0], 16, 0, 0); \
    __builtin_amdgcn_global_load_lds(                                         \
        (const __attribute__((address_space(1))) void*)pB1,                   \
        (__attribute__((address_space(3))) void*)&lds[(slotU) + 4096 + dst0], 16, 0, 0); \
    pB0 += 32; pB1 += 32; } while (0)

    // frag read base offsets (ushorts), loop-invariant per thread
    const int aIdx = (wm * 128 + r) * 32 + h * 8;  // + m*512 (+ kk*8192)
    const int bIdx = (wn * 64 + r) * 32 + h * 8;   // + n*512 (+ kk*8192 + 16384)

    f32x4 acc[8][4];
#pragma unroll
    for (int m = 0; m < 8; ++m)
#pragma unroll
        for (int n = 0; n < 4; ++n)
            acc[m][n] = f32x4{0.f, 0.f, 0.f, 0.f};

    // ---- prologue: 6 half-tiles (12 loads), then gate first K-tile
    STAGE_A(0);              // t0.A_k0   (K   0)
    STAGE_B(16384);          // t0.B_k0
    STAGE_A(8192);           // t0.A_k1   (K  32)
    STAGE_B(24576);          // t0.B_k1
    STAGE_A(32768 + 0);      // t1.A_k0   (K  64)
    STAGE_B(32768 + 16384);  // t1.B_k0
    VMC(8);                  // forces t0.A_k0, t0.B_k0 landed
    BAR();

    short8 aF[8], bF[4];

    // One K-tile = 4 phases; stages per phase: ph1->(t+1).A_k1, ph2->(t+1).B_k1,
    // ph3->(t+2).A_k0, ph4->(t+2).B_k0. Gates: end-ph2 & end-ph4 = vmcnt(8)
    // (tail: VMC(0)/VMC(4)), always immediately before the trailing barrier.
#define DO_TILE(P, tt)                                                              \
  {                                                                                 \
    /* ---- ph1 (kk=0, n0-1) ---- */                                                \
    _Pragma("unroll") for (int m = 0; m < 8; ++m)                                   \
        aF[m] = *(const short8*)&lds[(P) * 32768 + aIdx + m * 512];                 \
    bF[0] = *(const short8*)&lds[(P) * 32768 + 16384 + bIdx];                       \
    bF[1] = *(const short8*)&lds[(P) * 32768 + 16384 + bIdx + 512];                 \
    if ((tt) != NT - 1) STAGE_A(((P) ^ 1) * 32768 + 8192);                          \
    BAR(); LGKM0();                                                                 \
    __builtin_amdgcn_s_setprio(1);                                                  \
    _Pragma("unroll") for (int m = 0; m < 8; ++m) {                                 \
        acc[m][0] = __builtin_amdgcn_mfma_f32_16x16x32_bf16(aF[m], bF[0], acc[m][0], 0, 0, 0); \
        acc[m][1] = __builtin_amdgcn_mfma_f32_16x16x32_bf16(aF[m], bF[1], acc[m][1], 0, 0, 0); \
    }                                                                               \
    __builtin_amdgcn_s_setprio(0);                                                  \
    BAR();                                                                          \
    /* ---- ph2 (kk=0, n2-3) ---- */                                                \
    bF[2] = *(const short8*)&lds[(P) * 32768 + 16384 + bIdx + 1024];                \
    bF[3] = *(const short8*)&lds[(P) * 32768 + 16384 + bIdx + 1536];                \
    if ((tt) != NT - 1) STAGE_B(((P) ^ 1) * 32768 + 24576);                         \
    BAR(); LGKM0();                                                                 \
    __builtin_amdgcn_s_setprio(1);                                                  \
    _Pragma("unroll") for (int m = 0; m < 8; ++m) {                                 \
        acc[m][2] = __builtin_amdgcn_mfma_f32_16x16x32_bf16(aF[m], bF[2], acc[m][2], 0, 0, 0); \
        acc[m][3] = __builtin_amdgcn_mfma_f32_16x16x32_bf16(aF[m], bF[3], acc[m][3], 0, 0, 0); \
    }                                                                               \
    __builtin_amdgcn_s_setprio(0);                                                  \
    if ((tt) == NT - 1) { VMC(0); } else { VMC(8); }                                \
    BAR();                                                                          \
    /* ---- ph3 (kk=1, n0-1) ---- */                                                \
    _Pragma("unroll") for (int m = 0; m < 8; ++m)                                   \
        aF[m] = *(const short8*)&lds[(P) * 32768 + 8192 + aIdx + m * 512];          \
    bF[0] = *(const short8*)&lds[(P) * 32768 + 24576 + bIdx];                       \
    bF[1] = *(const short8*)&lds[(P) * 32768 + 24576 + bIdx + 512];                 \
    if ((tt) < NT - 2) STAGE_A((P) * 32768 + 0);                                    \
    BAR(); LGKM0();                                                                 \
    __builtin_amdgcn_s_setprio(1);                                                  \
    _Pragma("unroll") for (int m = 0; m < 8; ++m) {                                 \
        acc[m][0] = __builtin_amdgcn_mfma_f32_16x16x32_bf16(aF[m], bF[0], acc[m][0], 0, 0, 0); \
        acc[m][1] = __builtin_amdgcn_mfma_f32_16x16x32_bf16(aF[m], bF[1], acc[m][1], 0, 0, 0); \
    }                                                                               \
    __builtin_amdgcn_s_setprio(0);                                                  \
    BAR();                                                                          \
    /* ---- ph4 (kk=1, n2-3) ---- */                                                \
    bF[2] = *(const short8*)&lds[(P) * 32768 + 24576 + bIdx + 1024];                \
    bF[3] = *(const short8*)&lds[(P) * 32768 + 24576 + bIdx + 1536];                \
    if ((tt) < NT - 2) STAGE_B((P) * 32768 + 16384);                                \
    BAR(); LGKM0();                                                                 \
    __builtin_amdgcn_s_setprio(1);                                                  \
    _Pragma("unroll") for (int m = 0; m < 8; ++m) {                                 \
        acc[m][2] = __builtin_amdgcn_mfma_f32_16x16x32_bf16(aF[m], bF[2], acc[m][2], 0, 0, 0); \
        acc[m][3] = __builtin_amdgcn_mfma_f32_16x16x32_bf16(aF[m], bF[3], acc[m][3], 0, 0, 0); \
    }                                                                               \
    __builtin_amdgcn_s_setprio(0);                                                  \
    if ((tt) == NT - 2) { VMC(4); } else if ((tt) < NT - 2) { VMC(8); }             \
    BAR();                                                                          \
  }

#pragma unroll 1
    for (int tp = 0; tp < NT; tp += 2) {
        DO_TILE(0, tp);
        DO_TILE(1, tp + 1);
    }

    // ---- epilogue: bias + swish + extra bias, GroupNorm per 128-col group ----
    // acc[m][n][j]: row = wm*128 + m*16 + h*4 + j, col = wn*64 + n*16 + r
    const int colbase = bcol * BN + wn * 64;
    float bl[4], be[4], gwv[4], gbv[4];
#pragma unroll
    for (int n = 0; n < 4; ++n) {
        int col = colbase + n * 16 + r;
        bl[n] = bias_lin[col];
        be[n] = bias_extra[col];
        gwv[n] = gn_w[col];
        gbv[n] = gn_b[col];
    }

    float s1[8][4], s2[8][4];
#pragma unroll
    for (int m = 0; m < 8; ++m)
#pragma unroll
        for (int j = 0; j < 4; ++j) { s1[m][j] = 0.f; s2[m][j] = 0.f; }

#pragma unroll
    for (int m = 0; m < 8; ++m)
#pragma unroll
        for (int n = 0; n < 4; ++n)
#pragma unroll
            for (int j = 0; j < 4; ++j) {
                float z = acc[m][n][j] + bl[n];
                float sw = z / (1.f + __expf(-z)) + be[n];
                acc[m][n][j] = sw;
                s1[m][j] += sw;
                s2[m][j] += sw * sw;
            }

#pragma unroll
    for (int mask = 1; mask < 16; mask <<= 1) {
#pragma unroll
        for (int m = 0; m < 8; ++m)
#pragma unroll
            for (int j = 0; j < 4; ++j) {
                s1[m][j] += __shfl_xor(s1[m][j], mask, 16);
                s2[m][j] += __shfl_xor(s2[m][j], mask, 16);
            }
    }

    // stats exchange in LDS (tile data dead; nothing outstanding writes here)
    float* sred = (float*)lds;  // [2 stat][2 group-half][2 wave-pair][256 rows]
    const int gh = wn >> 1;
    const int p = wn & 1;
    if (r == 0) {
#pragma unroll
        for (int m = 0; m < 8; ++m)
#pragma unroll
            for (int j = 0; j < 4; ++j) {
                int row = wm * 128 + m * 16 + h * 4 + j;
                sred[((0 * 2 + gh) * 2 + p) * 256 + row] = s1[m][j];
                sred[((1 * 2 + gh) * 2 + p) * 256 + row] = s2[m][j];
            }
    }
    __syncthreads();

    const size_t orow0 = (size_t)brow * BM;
#pragma unroll
    for (int m = 0; m < 8; ++m)
#pragma unroll
        for (int j = 0; j < 4; ++j) {
            int row = wm * 128 + m * 16 + h * 4 + j;
            float mu = (sred[((0 * 2 + gh) * 2 + 0) * 256 + row] +
                        sred[((0 * 2 + gh) * 2 + 1) * 256 + row]) * (1.f / 128.f);
            float ex2 = (sred[((1 * 2 + gh) * 2 + 0) * 256 + row] +
                         sred[((1 * 2 + gh) * 2 + 1) * 256 + row]) * (1.f / 128.f);
            float var = ex2 - mu * mu;
            float rs = rsqrtf(var + 1e-5f);
            float* orow = out + (orow0 + row) * N_DIM;
#pragma unroll
            for (int n = 0; n < 4; ++n) {
                int col = colbase + n * 16 + r;
                orow[col] = (acc[m][n][j] - mu) * rs * gwv[n] + gbv[n];
            }
        }
}

extern "C" void kernel_launch(void* const* d_in, const int* in_sizes, int n_in,
                              void* d_out, int out_size, void* d_ws, size_t ws_size,
                              hipStream_t stream) {
    const float* x        = (const float*)d_in[0];
    const float* weight   = (const float*)d_in[1];
    const float* bias_lin = (const float*)d_in[2];
    const float* bias_ex  = (const float*)d_in[3];
    const float* gn_w     = (const float*)d_in[4];
    const float* gn_b     = (const float*)d_in[5];
    float* out = (float*)d_out;

    ushort* xb = (ushort*)d_ws;                     // 32 MiB bf16
    ushort* wb = xb + (size_t)M_DIM * K_DIM;        // 16 MiB bf16

    {
        int n8 = (M_DIM * K_DIM) / 8;
        f32_to_bf16_k<<<n8 / 256, 256, 0, stream>>>(x, xb, n8);
    }
    {
        int n8 = (N_DIM * K_DIM) / 8;
        f32_to_bf16_k<<<n8 / 256, 256, 0, stream>>>(weight, wb, n8);
    }

    (void)hipFuncSetAttribute((const void*)gemm_swish_gn,
                              hipFuncAttributeMaxDynamicSharedMemorySize, 131072);

    dim3 grid((M_DIM / BM) * (N_DIM / BN));  // 512 blocks
    gemm_swish_gn<<<grid, 512, 131072, stream>>>(xb, wb, bias_lin, bias_ex, gn_w, gn_b, out);
}